// Round 3
// 604.625 us; speedup vs baseline: 1.0989x; 1.0989x over previous
//
#include <hip/hip_runtime.h>
#include <cmath>

// Problem constants (from reference setup_inputs)
constexpr int B = 16, T = 2048, D = 2048, C = 100;
constexpr int NCHUNK = 16;           // t-chunks for colsum partials
constexpr int ROWS = T / NCHUNK;     // 128 rows per chunk
constexpr int TCH = 64;              // rows per block in btc kernel
#define EPS_F 1e-7f

// ---------------------------------------------------------------------------
// K1: feat column-sum partials for BOTH tensors, no atomics.
// grid = (D/1024, NCHUNK, 2*B), block = 256
// partials[((tensor*NCHUNK + chunk)*B + b)*D + d] = sum_{t in chunk} feat[b,t,d]
// ---------------------------------------------------------------------------
__global__ void colsum_kernel(const float* __restrict__ feat_act,
                              const float* __restrict__ feat_bkg,
                              float* __restrict__ partials) {
    const int z = blockIdx.z;            // tensor*B + b   (B == 16)
    const int tensor = z >> 4;
    const int b = z & (B - 1);
    const int chunk = blockIdx.y;
    const int d0 = (blockIdx.x * blockDim.x + threadIdx.x) * 4;
    const float* __restrict__ feat = tensor ? feat_bkg : feat_act;
    const float* base = feat + ((size_t)b * T + (size_t)chunk * ROWS) * D + d0;
    float4 acc = make_float4(0.f, 0.f, 0.f, 0.f);
    for (int t = 0; t < ROWS; ++t) {
        float4 v = *reinterpret_cast<const float4*>(base + (size_t)t * D);
        acc.x += v.x; acc.y += v.y; acc.z += v.z; acc.w += v.w;
    }
    float* o = partials + (((size_t)tensor * NCHUNK + chunk) * B + b) * D + d0;
    *reinterpret_cast<float4*>(o) = acc;        // non-atomic: unique slot per block
}

// ---------------------------------------------------------------------------
// Shared helper: 256-thread block reduce
// ---------------------------------------------------------------------------
__device__ __forceinline__ float block_reduce256(float v, float* sdata) {
    int tid = threadIdx.x;
    sdata[tid] = v;
    __syncthreads();
    for (int s = 128; s > 0; s >>= 1) {
        if (tid < s) sdata[tid] += sdata[tid + s];
        __syncthreads();
    }
    float r = sdata[0];
    __syncthreads();
    return r;
}

// ---------------------------------------------------------------------------
// K2: fused pass over the [B,T,C] tensors (gt, sup_cas, cas_s, cas_t).
//  - sup stats: per-(b,c) sumsq of (sup - (gt>0.5)) and positive count,
//    accumulated in LDS bins, one global atomic per (b,c) per block.
//  - st: sum of (cas_s - cas_t)^2, one global atomic per block.
// grid = (T/TCH, B), block = 256
// ---------------------------------------------------------------------------
__global__ void btc_kernel(const float* __restrict__ gt,
                           const float* __restrict__ sup,
                           const float* __restrict__ cs,
                           const float* __restrict__ ct,
                           float* __restrict__ sup_sumsq,
                           float* __restrict__ sup_cnt,
                           float* __restrict__ st_acc) {
    __shared__ float s_ss[C];
    __shared__ float s_cn[C];
    __shared__ float wsum[4];
    const int b = blockIdx.y;
    const int t0 = blockIdx.x * TCH;
    const int tid = threadIdx.x;
    if (tid < C) { s_ss[tid] = 0.f; s_cn[tid] = 0.f; }
    __syncthreads();

    const size_t base = ((size_t)b * T + t0) * C;
    float st_local = 0.f;
    for (int i = tid; i < TCH * C; i += 256) {   // exactly 25 iterations
        size_t idx = base + i;
        float g = gt[idx];
        float s = sup[idx];
        float a = cs[idx];
        float t = ct[idx];
        float m = (g > 0.5f) ? 1.f : 0.f;
        float d = s - m;
        int c = i % C;
        atomicAdd(&s_ss[c], d * d);
        atomicAdd(&s_cn[c], m);
        float e = a - t;
        st_local += e * e;
    }
    // wave (64-lane) reduce for st
    for (int off = 32; off; off >>= 1) st_local += __shfl_down(st_local, off, 64);
    int lane = tid & 63, wv = tid >> 6;
    if (lane == 0) wsum[wv] = st_local;
    __syncthreads();                 // also fences the LDS atomics above
    if (tid < C) {
        atomicAdd(&sup_sumsq[b * C + tid], s_ss[tid]);
        atomicAdd(&sup_cnt[b * C + tid], s_cn[tid]);
    }
    if (tid == 0) {
        atomicAdd(st_acc, wsum[0] + wsum[1] + wsum[2] + wsum[3]);
    }
}

// ---------------------------------------------------------------------------
// K3: reduce colsum partials -> ||mean_t feat||_2 per (tensor, b).
// grid = 2*B blocks, block = 256.  norms[tensor*B + b]
// ---------------------------------------------------------------------------
__global__ void norm_kernel(const float* __restrict__ partials,
                            float* __restrict__ norms) {
    __shared__ float sdata[256];
    const int z = blockIdx.x;            // tensor*B + b
    const int tensor = z >> 4;
    const int b = z & (B - 1);
    const int tid = threadIdx.x;
    const float invT = 1.f / (float)T;
    float acc = 0.f;
    for (int d0 = tid * 4; d0 < D; d0 += 1024) {   // 2 iterations
        float4 s = make_float4(0.f, 0.f, 0.f, 0.f);
        for (int ch = 0; ch < NCHUNK; ++ch) {
            const float4 v = *reinterpret_cast<const float4*>(
                partials + (((size_t)tensor * NCHUNK + ch) * B + b) * D + d0);
            s.x += v.x; s.y += v.y; s.z += v.z; s.w += v.w;
        }
        float mx = s.x * invT, my = s.y * invT, mz = s.z * invT, mw = s.w * invT;
        acc += mx * mx + my * my + mz * mz + mw * mw;
    }
    float total = block_reduce256(acc, sdata);
    if (tid == 0) norms[z] = sqrtf(total);
}

// ---------------------------------------------------------------------------
// K4: final single-block finishing: BCEs, um, sup, st, outputs.
// ---------------------------------------------------------------------------
__global__ void final_kernel(const float* __restrict__ score_act,
                             const float* __restrict__ score_bkg,
                             const float* __restrict__ label,
                             const float* __restrict__ norms,
                             const float* __restrict__ sup_sumsq,
                             const float* __restrict__ sup_cnt,
                             const float* __restrict__ st_acc,
                             float* __restrict__ out) {
    __shared__ float sdata[256];
    __shared__ float rowsum[B];
    const int tid = threadIdx.x;
    const int N = B * C;

    // label row sums
    if (tid < B) rowsum[tid] = 0.f;
    __syncthreads();
    for (int i = tid; i < N; i += 256) atomicAdd(&rowsum[i / C], label[i]);
    __syncthreads();

    // loss_cls: BCE(score_act, label / rowsum)
    float lc = 0.f;
    for (int i = tid; i < N; i += 256) {
        float tgt = label[i] / rowsum[i / C];
        float p = fminf(fmaxf(score_act[i], EPS_F), 1.f - EPS_F);
        lc -= tgt * logf(p) + (1.f - tgt) * log1pf(-p);
    }
    float loss_cls = block_reduce256(lc, sdata) / (float)N;

    // loss_be: BCE(score_bkg, 1/C)
    float lb = 0.f;
    const float u = 1.f / (float)C;
    for (int i = tid; i < N; i += 256) {
        float p = fminf(fmaxf(score_bkg[i], EPS_F), 1.f - EPS_F);
        lb -= u * logf(p) + (1.f - u) * log1pf(-p);
    }
    float loss_be = block_reduce256(lb, sdata) / (float)N;

    // loss_sup
    float ss = 0.f, sc = 0.f;
    for (int i = tid; i < N; i += 256) {
        if (sup_cnt[i] > 0.f) { ss += sqrtf(sup_sumsq[i]); sc += 1.f; }
    }
    float sup_sum = block_reduce256(ss, sdata);
    float sup_count = block_reduce256(sc, sdata);

    if (tid == 0) {
        float loss_um = 0.f;
        for (int b = 0; b < B; ++b) {
            float an = norms[b];          // tensor 0 = act
            float bn = norms[B + b];      // tensor 1 = bkg
            float la = fmaxf(100.f - an, 0.f);
            float v = la + bn;
            loss_um += v * v;
        }
        loss_um /= (float)B;
        float loss_sup = sup_sum / fmaxf(sup_count, 1.f);
        float loss_st = *st_acc / (float)((size_t)B * T * C);
        float total = loss_cls + 0.0005f * loss_um + 1.0f * loss_be
                    + 1.0f * loss_sup + 1.0f * loss_st;
        out[0] = total;
        out[1] = loss_cls;
        out[2] = loss_be;
        out[3] = loss_um;
        out[4] = loss_sup;
        out[5] = loss_st;
    }
}

// ---------------------------------------------------------------------------
extern "C" void kernel_launch(void* const* d_in, const int* in_sizes, int n_in,
                              void* d_out, int out_size, void* d_ws, size_t ws_size,
                              hipStream_t stream) {
    const float* score_act = (const float*)d_in[0];
    const float* score_bkg = (const float*)d_in[1];
    const float* feat_act  = (const float*)d_in[2];
    const float* feat_bkg  = (const float*)d_in[3];
    const float* label     = (const float*)d_in[4];
    const float* gt        = (const float*)d_in[5];
    const float* sup_cas   = (const float*)d_in[6];
    const float* cas_s     = (const float*)d_in[7];
    const float* cas_t     = (const float*)d_in[8];
    float* out = (float*)d_out;
    float* ws  = (float*)d_ws;

    // workspace layout (floats):
    //   [0,1600)      sup_sumsq[B*C]
    //   [1600,3200)   sup_cnt[B*C]
    //   [3200]        st_acc
    //   [3216,3248)   norms[2*B]
    //   [4096, ...)   colsum partials [2][NCHUNK][B][D]  (4 MiB, fully overwritten)
    float* sup_sumsq = ws;
    float* sup_cnt   = ws + 1600;
    float* st_acc    = ws + 3200;
    float* norms     = ws + 3216;
    float* partials  = ws + 4096;

    // Only the atomically-accumulated region needs zeroing (12.8 KB).
    hipMemsetAsync(d_ws, 0, 3201 * sizeof(float), stream);

    {   // feat column sums (both tensors, one launch, no atomics)
        dim3 grid(D / (256 * 4), NCHUNK, 2 * B);   // (2, 16, 32) = 1024 blocks
        colsum_kernel<<<grid, 256, 0, stream>>>(feat_act, feat_bkg, partials);
    }
    {   // fused pass over [B,T,C] tensors: sup stats + st sumsq
        dim3 grid(T / TCH, B);                     // (32, 16) = 512 blocks
        btc_kernel<<<grid, 256, 0, stream>>>(gt, sup_cas, cas_s, cas_t,
                                             sup_sumsq, sup_cnt, st_acc);
    }
    // reduce partials -> norms (depends on colsum)
    norm_kernel<<<dim3(2 * B), 256, 0, stream>>>(partials, norms);

    final_kernel<<<1, 256, 0, stream>>>(score_act, score_bkg, label, norms,
                                        sup_sumsq, sup_cnt, st_acc, out);
}